// Round 16
// baseline (259.462 us; speedup 1.0000x reference)
//
#include <hip/hip_runtime.h>
#include <hip/hip_bf16.h>

typedef unsigned short u16;
typedef unsigned int u32;
typedef __attribute__((ext_vector_type(8))) short bs8;   // 8 x bf16 MFMA frag
typedef __attribute__((ext_vector_type(4))) float fx4;   // MFMA accum frag
typedef __attribute__((ext_vector_type(4))) float f4_t;  // 16B fp32 load
typedef __attribute__((ext_vector_type(4))) unsigned int u4_t;

#define HDIM 2048
#define NCH 8

__device__ inline u16 f2bf(float f) {
  __hip_bfloat16 h = __float2bfloat16(f);
  return __builtin_bit_cast(u16, h);
}
__device__ inline float bf2f(u16 u) {
  __hip_bfloat16 h = __builtin_bit_cast(__hip_bfloat16, u);
  return __bfloat162float(h);
}
__device__ inline float pow2i(int e) {  // exact 2^e
  return __builtin_bit_cast(float, (unsigned)((127 + e) << 23));
}
__device__ inline void gld_lds16(const void* g, void* l) {
  __builtin_amdgcn_global_load_lds((const __attribute__((address_space(1))) void*)g,
                                   (__attribute__((address_space(3))) void*)l, 16, 0, 0);
}

// ---- weight int4 quant (ints in bf16) + fused cbw = bias-chunk @ W^T -----
__global__ __launch_bounds__(256) void k_wquant_cbw(
    const float* __restrict__ w0, const float* __restrict__ w1,
    const float* __restrict__ w2, const float* __restrict__ bias,
    u16* __restrict__ wq, float* __restrict__ sw, float* __restrict__ cbw,
    int NC) {
  int o = blockIdx.x, t = threadIdx.x;
  const float* w = (o < 2048) ? w0 : ((o < 4096) ? w1 : w2);
  const float* wrow = w + (size_t)(o & 2047) * HDIM;
  const f4_t* row4 = (const f4_t*)wrow;
  f4_t x0 = row4[2 * t], x1 = row4[2 * t + 1];
  float am = 0.f;
#pragma unroll
  for (int j = 0; j < 4; j++) { am = fmaxf(am, fabsf(x0[j])); am = fmaxf(am, fabsf(x1[j])); }
#pragma unroll
  for (int m = 1; m < 64; m <<= 1) am = fmaxf(am, __shfl_xor(am, m));
  __shared__ float red[4];
  if ((t & 63) == 0) red[t >> 6] = am;
  __syncthreads();
  am = fmaxf(fmaxf(red[0], red[1]), fmaxf(red[2], red[3]));
  float s = fmaxf(am / 7.0f, 1e-9f);
  if (t == 0) sw[o] = s;
  bs8 ov;
#pragma unroll
  for (int j = 0; j < 4; j++) {
    float q0 = fminf(fmaxf(rintf(x0[j] / s), -8.f), 7.f);
    float q1 = fminf(fmaxf(rintf(x1[j] / s), -8.f), 7.f);
    ov[j]     = (short)f2bf(q0);      // integer, exact in bf16
    ov[j + 4] = (short)f2bf(q1);
  }
  ((bs8*)(wq + (size_t)o * HDIM))[t] = ov;
  // fused cbw: acc[c] = dot(bias[c,:], w[o,:]) (fp32)
  float acc[NCH];
#pragma unroll
  for (int c = 0; c < NCH; c++) {
    const f4_t* bc = (const f4_t*)(bias + (size_t)c * HDIM);
    f4_t b0 = bc[2 * t], b1 = bc[2 * t + 1];
    float a = 0.f;
#pragma unroll
    for (int j = 0; j < 4; j++) a += x0[j] * b0[j] + x1[j] * b1[j];
    acc[c] = a;
  }
  __shared__ float redc[NCH][4];
#pragma unroll
  for (int c = 0; c < NCH; c++) {
    float a = acc[c];
#pragma unroll
    for (int m = 1; m < 64; m <<= 1) a += __shfl_xor(a, m);
    if ((t & 63) == 0) redc[c][t >> 6] = a;
  }
  __syncthreads();
  if (t < NCH) cbw[t * NC + o] = redc[t][0] + redc[t][1] + redc[t][2] + redc[t][3];
}

// ---- chunk stats, partial pass: 512 blocks (8 ch x 8 slice x 8 rowgrp) ---
__global__ __launch_bounds__(256) void k_stats_p(const float* __restrict__ x,
                                                 float* __restrict__ pmx,
                                                 float* __restrict__ pmn) {
  int rg = blockIdx.x & 7;
  int sl = (blockIdx.x >> 3) & 7;
  int ch = blockIdx.x >> 6;
  int c = (sl << 8) + threadIdx.x;
  const float* base = x + ((size_t)ch * 256 + rg * 32) * HDIM + c;
  float mx = -1e30f, mn = 1e30f;
  for (int r = 0; r < 32; r++) { float v = base[(size_t)r * HDIM]; mx = fmaxf(mx, v); mn = fminf(mn, v); }
  pmx[(size_t)(rg * 8 + ch) * HDIM + c] = mx;
  pmn[(size_t)(rg * 8 + ch) * HDIM + c] = mn;
}

// ---- combine partials -> bias, cmax (one pass, exact) --------------------
__global__ __launch_bounds__(256) void k_stats_c(const float* __restrict__ pmx,
                                                 const float* __restrict__ pmn,
                                                 float* __restrict__ biasO,
                                                 float* __restrict__ cmaxO) {
  int ch = blockIdx.x >> 3;
  int c = ((blockIdx.x & 7) << 8) + threadIdx.x;
  float mx = -1e30f, mn = 1e30f;
#pragma unroll
  for (int rg = 0; rg < 8; rg++) {
    mx = fmaxf(mx, pmx[(size_t)(rg * 8 + ch) * HDIM + c]);
    mn = fminf(mn, pmn[(size_t)(rg * 8 + ch) * HDIM + c]);
  }
  float bi = (mx + mn) * 0.5f;
  biasO[ch * HDIM + c] = bi;
  cmaxO[ch * HDIM + c] = fmaxf(mx - bi, bi - mn);
}

// ---- tmax reduce + per-channel scale s, e2 = 2^idx, tc = (tmax/7)*2^-7 ---
__global__ __launch_bounds__(256) void k_tscale(const float* __restrict__ cmax,
                                                float* __restrict__ scaleO,
                                                float* __restrict__ e2O,
                                                float* __restrict__ tcO) {
  int ch = blockIdx.x, t = threadIdx.x;
  const float* cr = cmax + ch * HDIM;
  float v[8];
  float mx = 0.f;
#pragma unroll
  for (int i = 0; i < 8; i++) { v[i] = cr[i * 256 + t]; mx = fmaxf(mx, v[i]); }
#pragma unroll
  for (int m = 1; m < 64; m <<= 1) mx = fmaxf(mx, __shfl_xor(mx, m));
  __shared__ float red[4];
  __shared__ float tms;
  if ((t & 63) == 0) red[t >> 6] = mx;
  __syncthreads();
  if (t == 0) tms = fmaxf(fmaxf(red[0], red[1]), fmaxf(red[2], red[3]));
  __syncthreads();
  float tmax = tms;
  if (t == 0) tcO[ch] = (tmax / 7.0f) * pow2i(-7);
#pragma unroll
  for (int i = 0; i < 8; i++) {
    int idx = 0;
#pragma unroll
    for (int k = 0; k < 7; k++) idx += (v[i] > tmax * pow2i(k - 7)) ? 1 : 0;
    float s = (tmax * pow2i(idx - 7)) / 7.0f;   // == reference fl(scale)
    scaleO[ch * HDIM + i * 256 + t] = fmaxf(s, 1e-9f);
    e2O[ch * HDIM + i * 256 + t] = pow2i(idx);
  }
}

// ---- activation quant: A' = round((x-bias)/s)*2^idx, bf16-exact ints -----
__global__ __launch_bounds__(256) void k_qdq(const float* __restrict__ x,
                                             const float* __restrict__ bias,
                                             const float* __restrict__ scale,
                                             const float* __restrict__ e2,
                                             u16* __restrict__ out) {
  int row = blockIdx.x, t = threadIdx.x;
  int ch = row >> 8;
  const f4_t* xr = (const f4_t*)(x + (size_t)row * HDIM);
  const f4_t* br = (const f4_t*)(bias + (size_t)ch * HDIM);
  const f4_t* sr = (const f4_t*)(scale + (size_t)ch * HDIM);
  const f4_t* er = (const f4_t*)(e2 + (size_t)ch * HDIM);
  f4_t x0 = xr[2 * t], x1 = xr[2 * t + 1];
  f4_t b0 = br[2 * t], b1 = br[2 * t + 1];
  f4_t s0 = sr[2 * t], s1 = sr[2 * t + 1];
  f4_t e0 = er[2 * t], e1 = er[2 * t + 1];
  bs8 ov;
#pragma unroll
  for (int j = 0; j < 4; j++) {
    float q0 = fminf(fmaxf(rintf((x0[j] - b0[j]) / s0[j]), -8.f), 7.f);
    ov[j] = (short)f2bf(q0 * e0[j]);            // q*2^idx: exact
    float q1 = fminf(fmaxf(rintf((x1[j] - b1[j]) / s1[j]), -8.f), 7.f);
    ov[j + 4] = (short)f2bf(q1 * e1[j]);
  }
  ((bs8*)(out + (size_t)row * HDIM))[t] = ov;
}

// ---- QKV GEMM: 64x128 tile, BK=64, XOR-swizzled LDS, 6 blocks/CU ---------
__global__ __launch_bounds__(256) void k_gemm(
    const u16* __restrict__ A, const u16* __restrict__ B,
    float* __restrict__ o0, float* __restrict__ o1, float* __restrict__ o2,
    const float* __restrict__ cbw, int NC,
    const float* __restrict__ bb0, const float* __restrict__ bb1,
    const float* __restrict__ bb2,
    const float* __restrict__ tc, const float* __restrict__ sw,
    float scl0, float scl1, float scl2) {
  __shared__ u16 smA[64 * 64];
  __shared__ u16 smB[128 * 64];
  int tid = threadIdx.x;
  int wave = tid >> 6, lane = tid & 63;
  int wr = wave >> 1, wc = wave & 1;
  int row0 = blockIdx.y * 64, col0 = blockIdx.x * 128;
  int mat = col0 >> 11;
  float* out = (mat == 0) ? o0 : ((mat == 1) ? o1 : o2);
  const float* bias = (mat == 0) ? bb0 : ((mat == 1) ? bb1 : bb2);
  float scl = (mat == 0) ? scl0 : ((mat == 1) ? scl1 : scl2);
  int chunk = row0 >> 8;
  fx4 zz = {0.f, 0.f, 0.f, 0.f};
  fx4 acc[2][4];
#pragma unroll
  for (int m = 0; m < 2; m++)
#pragma unroll
    for (int n = 0; n < 4; n++) acc[m][n] = zz;

  int srow = wave * 8 + (lane >> 3);
  int scol = (((lane & 7) ^ (lane >> 3)) << 3);
  const u16* Ab = A + (size_t)row0 * HDIM;
  const u16* Bb = B + (size_t)col0 * HDIM;

  int arow = wr * 32 + (lane & 15);
  int brow = wc * 64 + (lane & 15);
  int xA = (arow & 7) << 4;
  int xB = (brow & 7) << 4;
  int kB0 = (lane >> 4) << 4;

  for (int kt = 0; kt < 32; kt++) {
    int kb = kt * 64 + scol;
#pragma unroll
    for (int r = 0; r < 2; r++)
      gld_lds16(Ab + (size_t)(r * 32 + srow) * HDIM + kb,
                (char*)smA + (r * 32 + wave * 8) * 128);
#pragma unroll
    for (int r = 0; r < 4; r++)
      gld_lds16(Bb + (size_t)(r * 32 + srow) * HDIM + kb,
                (char*)smB + (r * 32 + wave * 8) * 128);
    __syncthreads();
#pragma unroll
    for (int kk = 0; kk < 2; kk++) {
      bs8 af[2], bfr[4];
#pragma unroll
      for (int m = 0; m < 2; m++)
        af[m] = *(const bs8*)((const char*)smA + (size_t)((arow + m * 16) * 128 +
                                ((kk * 64 + kB0) ^ xA)));
#pragma unroll
      for (int n = 0; n < 4; n++)
        bfr[n] = *(const bs8*)((const char*)smB + (size_t)((brow + n * 16) * 128 +
                                ((kk * 64 + kB0) ^ xB)));
#pragma unroll
      for (int m = 0; m < 2; m++)
#pragma unroll
        for (int n = 0; n < 4; n++)
          acc[m][n] = __builtin_amdgcn_mfma_f32_16x16x32_bf16(af[m], bfr[n], acc[m][n], 0, 0, 0);
    }
    __syncthreads();
  }
  float tcv = tc[chunk];
  int colb = col0 + wc * 64 + (lane & 15);        // global col
  int rowb = row0 + wr * 32 + ((lane >> 4) << 2);
#pragma unroll
  for (int m = 0; m < 2; m++) {
#pragma unroll
    for (int n = 0; n < 4; n++) {
      int colg = colb + n * 16;
      int colL = colg - (mat << 11);
      float sc = tcv * sw[colg];
      float cb = cbw[chunk * NC + colg] + bias[colL];
#pragma unroll
      for (int j = 0; j < 4; j++) {
        int row = rowb + m * 16 + j;
        out[(size_t)row * HDIM + colL] = (acc[m][n][j] * sc + cb) * scl;
      }
    }
  }
}

// ---- split-K O-GEMM: 64x128 tile, BK=64, K thirds -> raw exact-int -------
__global__ __launch_bounds__(256) void k_gemm_sk(const u16* __restrict__ A,
                                                 const u16* __restrict__ B,
                                                 float* __restrict__ p0,
                                                 float* __restrict__ p1,
                                                 float* __restrict__ p2) {
  __shared__ u16 smA[64 * 64];
  __shared__ u16 smB[128 * 64];
  int tid = threadIdx.x;
  int wave = tid >> 6, lane = tid & 63;
  int wr = wave >> 1, wc = wave & 1;
  int row0 = blockIdx.y * 64, col0 = blockIdx.x * 128;
  int z = blockIdx.z;
  float* out = (z == 0) ? p0 : ((z == 1) ? p1 : p2);
  int kt0 = z * 11;
  int kt1 = (z == 2) ? 32 : (z * 11 + 11);
  fx4 zz = {0.f, 0.f, 0.f, 0.f};
  fx4 acc[2][4];
#pragma unroll
  for (int m = 0; m < 2; m++)
#pragma unroll
    for (int n = 0; n < 4; n++) acc[m][n] = zz;

  int srow = wave * 8 + (lane >> 3);
  int scol = (((lane & 7) ^ (lane >> 3)) << 3);
  const u16* Ab = A + (size_t)row0 * HDIM;
  const u16* Bb = B + (size_t)col0 * HDIM;

  int arow = wr * 32 + (lane & 15);
  int brow = wc * 64 + (lane & 15);
  int xA = (arow & 7) << 4;
  int xB = (brow & 7) << 4;
  int kB0 = (lane >> 4) << 4;

  for (int kt = kt0; kt < kt1; kt++) {
    int kb = kt * 64 + scol;
#pragma unroll
    for (int r = 0; r < 2; r++)
      gld_lds16(Ab + (size_t)(r * 32 + srow) * HDIM + kb,
                (char*)smA + (r * 32 + wave * 8) * 128);
#pragma unroll
    for (int r = 0; r < 4; r++)
      gld_lds16(Bb + (size_t)(r * 32 + srow) * HDIM + kb,
                (char*)smB + (r * 32 + wave * 8) * 128);
    __syncthreads();
#pragma unroll
    for (int kk = 0; kk < 2; kk++) {
      bs8 af[2], bfr[4];
#pragma unroll
      for (int m = 0; m < 2; m++)
        af[m] = *(const bs8*)((const char*)smA + (size_t)((arow + m * 16) * 128 +
                                ((kk * 64 + kB0) ^ xA)));
#pragma unroll
      for (int n = 0; n < 4; n++)
        bfr[n] = *(const bs8*)((const char*)smB + (size_t)((brow + n * 16) * 128 +
                                ((kk * 64 + kB0) ^ xB)));
#pragma unroll
      for (int m = 0; m < 2; m++)
#pragma unroll
        for (int n = 0; n < 4; n++)
          acc[m][n] = __builtin_amdgcn_mfma_f32_16x16x32_bf16(af[m], bfr[n], acc[m][n], 0, 0, 0);
    }
    __syncthreads();
  }
  int colb = col0 + wc * 64 + (lane & 15);
  int rowb = row0 + wr * 32 + ((lane >> 4) << 2);
#pragma unroll
  for (int m = 0; m < 2; m++)
#pragma unroll
    for (int n = 0; n < 4; n++)
#pragma unroll
      for (int j = 0; j < 4; j++)
        out[(size_t)(rowb + m * 16 + j) * HDIM + colb + n * 16] = acc[m][n][j];
}

// ---- split-K combine + epilogue: out = ((p0+p1+p2)*sc + cb) -------------
__global__ __launch_bounds__(256) void k_fin(const float* __restrict__ p0,
                                             const float* __restrict__ p1,
                                             const float* __restrict__ p2,
                                             const float* __restrict__ cbw,
                                             const float* __restrict__ bias,
                                             const float* __restrict__ tc,
                                             const float* __restrict__ sw,
                                             float* __restrict__ out) {
  int row = blockIdx.x, t = threadIdx.x;
  int chunk = row >> 8;
  float tcv = tc[chunk];
  const f4_t* a = (const f4_t*)(p0 + (size_t)row * HDIM);
  const f4_t* b = (const f4_t*)(p1 + (size_t)row * HDIM);
  const f4_t* c_ = (const f4_t*)(p2 + (size_t)row * HDIM);
  f4_t* o = (f4_t*)(out + (size_t)row * HDIM);
#pragma unroll
  for (int u = 0; u < 2; u++) {
    f4_t x = a[2 * t + u], y = b[2 * t + u], w = c_[2 * t + u];
    f4_t r;
#pragma unroll
    for (int j = 0; j < 4; j++) {
      int c = (2 * t + u) * 4 + j;
      float sc = tcv * sw[c];
      float cb = cbw[chunk * HDIM + c] + bias[c];
      r[j] = ((x[j] + y[j] + w[j]) * sc + cb) * 1.0f;
    }
    o[2 * t + u] = r;
  }
}

// ---- K/V hi-lo split + V transpose, pre-swizzled tile layout (ONCE) ------
__global__ __launch_bounds__(256) void k_split(const float* __restrict__ Kf,
                                               const float* __restrict__ Vf,
                                               u16* __restrict__ Khg,
                                               u16* __restrict__ Klg,
                                               u16* __restrict__ Vhg,
                                               u16* __restrict__ Vlg) {
  __shared__ u16 Th[4096], Tl[4096];
  int t = threadIdx.x;
  int ti = blockIdx.x & 15, h = (blockIdx.x >> 4) & 31, b = blockIdx.x >> 9;
  size_t rowStart = (size_t)b * 1024 + ti * 64;
  int colh = h * 64;
  size_t tbase = ((size_t)((b * 32 + h) * 16 + ti)) * 4096;
  int kr = t >> 2, d0 = (t & 3) << 4;
  int xk = (kr & 7) << 3;
  const float* kp = Kf + (rowStart + kr) * HDIM + colh + d0;
  const float* vp = Vf + (rowStart + kr) * HDIM + colh + d0;
  f4_t kv[4], vv[4];
#pragma unroll
  for (int qd = 0; qd < 4; qd++) { kv[qd] = *(const f4_t*)(kp + 4 * qd); vv[qd] = *(const f4_t*)(vp + 4 * qd); }
  bs8 h0, l0, h1, l1;
#pragma unroll
  for (int j = 0; j < 4; j++) {
    float x = kv[0][j]; u16 hh = f2bf(x); h0[j] = (short)hh; l0[j] = (short)f2bf(x - bf2f(hh));
    x = kv[1][j]; hh = f2bf(x); h0[j + 4] = (short)hh; l0[j + 4] = (short)f2bf(x - bf2f(hh));
    x = kv[2][j]; hh = f2bf(x); h1[j] = (short)hh; l1[j] = (short)f2bf(x - bf2f(hh));
    x = kv[3][j]; hh = f2bf(x); h1[j + 4] = (short)hh; l1[j + 4] = (short)f2bf(x - bf2f(hh));
  }
  *(bs8*)(Khg + tbase + kr * 64 + (d0 ^ xk)) = h0;
  *(bs8*)(Klg + tbase + kr * 64 + (d0 ^ xk)) = l0;
  *(bs8*)(Khg + tbase + kr * 64 + ((d0 + 8) ^ xk)) = h1;
  *(bs8*)(Klg + tbase + kr * 64 + ((d0 + 8) ^ xk)) = l1;
#pragma unroll
  for (int qd = 0; qd < 4; qd++)
#pragma unroll
    for (int j = 0; j < 4; j++) {
      int d = d0 + 4 * qd + j;
      float x = vv[qd][j]; u16 hh = f2bf(x);
      int vi = d * 64 + (kr ^ ((d & 7) << 3));
      Th[vi] = hh; Tl[vi] = f2bf(x - bf2f(hh));
    }
  __syncthreads();
  *(bs8*)(Vhg + tbase + t * 16) = *(const bs8*)&Th[t * 16];
  *(bs8*)(Vhg + tbase + t * 16 + 8) = *(const bs8*)&Th[t * 16 + 8];
  *(bs8*)(Vlg + tbase + t * 16) = *(const bs8*)&Tl[t * 16];
  *(bs8*)(Vlg + tbase + t * 16 + 8) = *(const bs8*)&Tl[t * 16 + 8];
}

// ---- flash attention, swapped QK^T + T14 async-STAGE (reg prefetch) ------
// Staging: tile ti+1 loaded into regs while tile ti computes; regs written
// to LDS (same bytes/addresses as the gld_lds path) at loop top. Barrier
// count unchanged; LDS image and all math bit-identical to rounds 8-15.
__global__ __launch_bounds__(256) void k_attn(const float* __restrict__ Q,
                                              const u16* __restrict__ Khg,
                                              const u16* __restrict__ Klg,
                                              const u16* __restrict__ Vhg,
                                              const u16* __restrict__ Vlg,
                                              float* __restrict__ O) {
  __shared__ u16 Kh[64 * 64], Kl[64 * 64];   // [key][d^((key&7)<<3)]
  __shared__ u16 Vh[64 * 64], Vl[64 * 64];   // [d][key^((d&7)<<3)]
  int tid = threadIdx.x, wave = tid >> 6, lane = tid & 63;
  int l15 = lane & 15, l4 = lane >> 4;
  int lid = blockIdx.x;
  int xcd = lid & 7, jj = lid >> 3;
  int pair = xcd * 8 + (jj >> 4);     // 64 (b,h) pairs; 8 per XCD
  int qt = jj & 15;                   // 16 q-tiles of 64 rows
  int h = pair & 31, b = pair >> 5;
  size_t rowStart = (size_t)b * 1024;
  int colh = h * 64;
  int qbase = qt * 64 + wave * 16;
  size_t hbase = (size_t)pair * 16 * 4096;   // element base of this (b,h)

  bs8 qh[2], ql[2];
#pragma unroll
  for (int kk = 0; kk < 2; kk++) {
    const float* qp = Q + (rowStart + qbase + l15) * HDIM + colh + kk * 32 + (l4 << 3);
    f4_t a0 = *(const f4_t*)qp;
    f4_t a1 = *(const f4_t*)(qp + 4);
#pragma unroll
    for (int j = 0; j < 4; j++) {
      float x = a0[j]; u16 hh = f2bf(x);
      qh[kk][j] = (short)hh; ql[kk][j] = (short)f2bf(x - bf2f(hh));
      x = a1[j]; hh = f2bf(x);
      qh[kk][j + 4] = (short)hh; ql[kk][j + 4] = (short)f2bf(x - bf2f(hh));
    }
  }

  fx4 zz = {0.f, 0.f, 0.f, 0.f};
  fx4 oacc[4];
  float mrun = -1e30f, lrun = 0.f;
#pragma unroll
  for (int n = 0; n < 4; n++) oacc[n] = zz;

  const u16* garr = (wave == 0) ? Khg : (wave == 1) ? Klg : (wave == 2) ? Vhg : Vlg;
  u16* larr = (wave == 0) ? Kh : (wave == 1) ? Kl : (wave == 2) ? Vh : Vl;

  int srcA = l15 + ((lane & 16) << 1);   // l15 + 32*(l4&1)
  int srcB = srcA + 16;
  int hiSel = l4 >> 1;

  // T14 prologue: tile 0 into regs
  f4_t pre[8];
  {
    const u16* gs = garr + hbase + lane * 8;
#pragma unroll
    for (int seg = 0; seg < 8; seg++) pre[seg] = *(const f4_t*)(gs + seg * 512);
  }

  for (int ti = 0; ti < 16; ti++) {
    // write staged regs to LDS (linear, same image as gld_lds path)
#pragma unroll
    for (int seg = 0; seg < 8; seg++)
      *(f4_t*)(larr + seg * 512 + lane * 8) = pre[seg];
    // issue next tile's global loads; latency hides under compute below
    if (ti + 1 < 16) {
      const u16* gs = garr + hbase + (size_t)(ti + 1) * 4096 + lane * 8;
#pragma unroll
      for (int seg = 0; seg < 8; seg++) pre[seg] = *(const f4_t*)(gs + seg * 512);
    }
    __syncthreads();

    fx4 sf[4];
#pragma unroll
    for (int n = 0; n < 4; n++) sf[n] = zz;
    __builtin_amdgcn_s_setprio(1);
#pragma unroll
    for (int kk = 0; kk < 2; kk++) {
      int colr = kk * 32 + (l4 << 3);
#pragma unroll
      for (int n = 0; n < 4; n++) {
        int row = n * 16 + l15;
        int ko = row * 64 + (colr ^ ((row & 7) << 3));
        bs8 bh = *(const bs8*)&Kh[ko];
        bs8 bl = *(const bs8*)&Kl[ko];
        sf[n] = __builtin_amdgcn_mfma_f32_16x16x32_bf16(bl, ql[kk], sf[n], 0, 0, 0);
        sf[n] = __builtin_amdgcn_mfma_f32_16x16x32_bf16(bh, ql[kk], sf[n], 0, 0, 0);
        sf[n] = __builtin_amdgcn_mfma_f32_16x16x32_bf16(bl, qh[kk], sf[n], 0, 0, 0);
        sf[n] = __builtin_amdgcn_mfma_f32_16x16x32_bf16(bh, qh[kk], sf[n], 0, 0, 0);
      }
    }
    __builtin_amdgcn_s_setprio(0);
    float tm = sf[0][0];
#pragma unroll
    for (int n = 0; n < 4; n++)
#pragma unroll
      for (int j = 0; j < 4; j++) tm = fmaxf(tm, sf[n][j]);
    tm = fmaxf(tm, __shfl_xor(tm, 16));
    tm = fmaxf(tm, __shfl_xor(tm, 32));
    float mn = fmaxf(mrun, tm);
    float corr = __expf(mrun - mn);
    mrun = mn;
    float rs = 0.f;
#pragma unroll
    for (int n = 0; n < 4; n++)
#pragma unroll
      for (int j = 0; j < 4; j++) { float p = __expf(sf[n][j] - mn); sf[n][j] = p; rs += p; }
    rs += __shfl_xor(rs, 16);
    rs += __shfl_xor(rs, 32);
    lrun = lrun * corr + rs;
#pragma unroll
    for (int n = 0; n < 4; n++)
#pragma unroll
      for (int j = 0; j < 4; j++) oacc[n][j] *= corr;

    u32 hiw[4][2], low[4][2];
#pragma unroll
    for (int n = 0; n < 4; n++) {
      u16 hh0 = f2bf(sf[n][0]), hh1 = f2bf(sf[n][1]);
      u16 hh2 = f2bf(sf[n][2]), hh3 = f2bf(sf[n][3]);
      u16 ll0 = f2bf(sf[n][0] - bf2f(hh0)), ll1 = f2bf(sf[n][1] - bf2f(hh1));
      u16 ll2 = f2bf(sf[n][2] - bf2f(hh2)), ll3 = f2bf(sf[n][3] - bf2f(hh3));
      hiw[n][0] = (u32)hh0 | ((u32)hh1 << 16);
      hiw[n][1] = (u32)hh2 | ((u32)hh3 << 16);
      low[n][0] = (u32)ll0 | ((u32)ll1 << 16);
      low[n][1] = (u32)ll2 | ((u32)ll3 << 16);
    }
    bs8 ph[2], pl[2];
#pragma unroll
    for (int kkv = 0; kkv < 2; kkv++) {
      u4_t wh, wl;
#pragma unroll
      for (int half = 0; half < 2; half++) {
        int src = half ? srcB : srcA;
#pragma unroll
        for (int pr = 0; pr < 2; pr++) {
          int a0 = __shfl((int)hiw[2 * kkv][pr], src);
          int a1 = __shfl((int)hiw[2 * kkv + 1][pr], src);
          wh[half * 2 + pr] = (u32)(hiSel ? a1 : a0);
          int b0 = __shfl((int)low[2 * kkv][pr], src);
          int b1 = __shfl((int)low[2 * kkv + 1][pr], src);
          wl[half * 2 + pr] = (u32)(hiSel ? b1 : b0);
        }
      }
      ph[kkv] = __builtin_bit_cast(bs8, wh);
      pl[kkv] = __builtin_bit_cast(bs8, wl);
    }

    __builtin_amdgcn_s_setprio(1);
#pragma unroll
    for (int kkv = 0; kkv < 2; kkv++) {
      int colr = kkv * 32 + (l4 << 3);
#pragma unroll
      for (int n = 0; n < 4; n++) {
        int vrow = n * 16 + l15;
        int vo = vrow * 64 + (colr ^ ((vrow & 7) << 3));
        bs8 vh = *(const bs8*)&Vh[vo];
        bs8 vl = *(const bs8*)&Vl[vo];
        oacc[n] = __builtin_amdgcn_mfma_f32_16x16x32_bf16(vl, pl[kkv], oacc[n], 0, 0, 0);
        oacc[n] = __builtin_amdgcn_mfma_f32_16x16x32_bf16(vh, pl[kkv], oacc[n], 0, 0, 0);
        oacc[n] = __builtin_amdgcn_mfma_f32_16x16x32_bf16(vl, ph[kkv], oacc[n], 0, 0, 0);
        oacc[n] = __builtin_amdgcn_mfma_f32_16x16x32_bf16(vh, ph[kkv], oacc[n], 0, 0, 0);
      }
    }
    __builtin_amdgcn_s_setprio(0);
    __syncthreads();
  }
  size_t token = rowStart + qbase + l15;
#pragma unroll
  for (int n = 0; n < 4; n++) {
    f4_t r;
#pragma unroll
    for (int j = 0; j < 4; j++) r[j] = oacc[n][j] / lrun;
    *(f4_t*)(O + token * HDIM + colh + n * 16 + (l4 << 2)) = r;
  }
}

extern "C" void kernel_launch(void* const* d_in, const int* in_sizes, int n_in,
                              void* d_out, int out_size, void* d_ws, size_t ws_size,
                              hipStream_t stream) {
  const float* hs = (const float*)d_in[0];
  const float* qw = (const float*)d_in[1];
  const float* kw = (const float*)d_in[2];
  const float* vw = (const float*)d_in[3];
  const float* ow = (const float*)d_in[4];
  const float* qb = (const float*)d_in[5];
  const float* kb = (const float*)d_in[6];
  const float* vb = (const float*)d_in[7];
  const float* ob = (const float*)d_in[8];

  char* ws = (char*)d_ws;
  const size_t MB = 1u << 20;
  // Timeline-shared workspace (ws >= 82 MB, proven rounds 3-15):
  //  [0,32MB):  A: wqQKV(24)+actA(8) -> B: K/V split arrays -> C: p0/p1
  //  [32,48MB): Qf (stage-2 stats partials after attn)
  //  [48,64MB): stage-1 stats partials -> Kf -> actA2
  //  [64,80MB): Vf -> wqO
  //  [80MB+):   small stats buffers     p2 = d_out (ctx dead after qdq)
  u16* wqQKV = (u16*)(ws + 0 * MB);
  u16* actA  = (u16*)(ws + 24 * MB);
  u16* Khg   = (u16*)(ws + 0 * MB);
  u16* Klg   = (u16*)(ws + 8 * MB);
  u16* Vhg   = (u16*)(ws + 16 * MB);
  u16* Vlg   = (u16*)(ws + 24 * MB);
  float* p0  = (float*)(ws + 0 * MB);
  float* p1  = (float*)(ws + 16 * MB);
  float* Qf  = (float*)(ws + 32 * MB);
  float* Kf  = (float*)(ws + 48 * MB);
  float* Vf  = (float*)(ws + 64 * MB);
  u16* actA2 = (u16*)(ws + 48 * MB);   // over Kf (free after k_split)
  u16* wqO   = (u16*)(ws + 64 * MB);   // over Vf (free after k_split)
  float* pmx1 = (float*)(ws + 48 * MB);          // stage-1 partials (pre-Kf)
  float* pmn1 = pmx1 + 64 * HDIM;
  float* pmx2 = (float*)(ws + 32 * MB);          // stage-2 partials (Qf dead)
  float* pmn2 = pmx2 + 64 * HDIM;
  float* sm  = (float*)(ws + 80 * MB);
  float* bias1  = sm;
  float* cmax1  = bias1 + NCH * HDIM;
  float* scale1 = cmax1 + NCH * HDIM;
  float* e2_1   = scale1 + NCH * HDIM;
  float* bias2  = e2_1 + NCH * HDIM;
  float* cmax2  = bias2 + NCH * HDIM;
  float* scale2 = cmax2 + NCH * HDIM;
  float* e2_2   = scale2 + NCH * HDIM;
  float* cbwQKV = e2_2 + NCH * HDIM;     // [NCH][6144]
  float* swQKV  = cbwQKV + NCH * 3 * HDIM;
  float* cbwO   = swQKV + 3 * HDIM;      // [NCH][2048]
  float* swO    = cbwO + NCH * HDIM;
  float* tc1    = swO + HDIM;
  float* tc2    = tc1 + NCH;
  float* ctx = (float*)d_out;
  float* p2  = (float*)d_out;            // ctx dead after stage-2 qdq

  k_stats_p<<<512, 256, 0, stream>>>(hs, pmx1, pmn1);
  k_stats_c<<<64, 256, 0, stream>>>(pmx1, pmn1, bias1, cmax1);
  k_tscale<<<8, 256, 0, stream>>>(cmax1, scale1, e2_1, tc1);
  k_qdq<<<2048, 256, 0, stream>>>(hs, bias1, scale1, e2_1, actA);
  k_wquant_cbw<<<6144, 256, 0, stream>>>(qw, kw, vw, bias1, wqQKV, swQKV, cbwQKV, 3 * HDIM);
  k_gemm<<<dim3(48, 32), 256, 0, stream>>>(actA, wqQKV, Qf, Kf, Vf,
                                           cbwQKV, 3 * HDIM, qb, kb, vb,
                                           tc1, swQKV, 0.125f, 1.0f, 1.0f);
  k_split<<<1024, 256, 0, stream>>>(Kf, Vf, Khg, Klg, Vhg, Vlg);
  k_attn<<<1024, 256, 0, stream>>>(Qf, Khg, Klg, Vhg, Vlg, ctx);
  k_stats_p<<<512, 256, 0, stream>>>(ctx, pmx2, pmn2);
  k_stats_c<<<64, 256, 0, stream>>>(pmx2, pmn2, bias2, cmax2);
  k_tscale<<<8, 256, 0, stream>>>(cmax2, scale2, e2_2, tc2);
  k_qdq<<<2048, 256, 0, stream>>>(ctx, bias2, scale2, e2_2, actA2);
  k_wquant_cbw<<<2048, 256, 0, stream>>>(ow, ow, ow, bias2, wqO, swO, cbwO, HDIM);
  k_gemm_sk<<<dim3(16, 32, 3), 256, 0, stream>>>(actA2, wqO, p0, p1, p2);
  k_fin<<<2048, 256, 0, stream>>>(p0, p1, p2, cbwO, ob, tc2, swO, (float*)d_out);
}

// Round 17
// 254.284 us; speedup vs baseline: 1.0204x; 1.0204x over previous
//
#include <hip/hip_runtime.h>
#include <hip/hip_bf16.h>

typedef unsigned short u16;
typedef unsigned int u32;
typedef __attribute__((ext_vector_type(8))) short bs8;   // 8 x bf16 MFMA frag
typedef __attribute__((ext_vector_type(4))) float fx4;   // MFMA accum frag
typedef __attribute__((ext_vector_type(4))) float f4_t;  // 16B fp32 load
typedef __attribute__((ext_vector_type(4))) unsigned int u4_t;

#define HDIM 2048
#define NCH 8

__device__ inline u16 f2bf(float f) {
  __hip_bfloat16 h = __float2bfloat16(f);
  return __builtin_bit_cast(u16, h);
}
__device__ inline float bf2f(u16 u) {
  __hip_bfloat16 h = __builtin_bit_cast(__hip_bfloat16, u);
  return __bfloat162float(h);
}
__device__ inline float pow2i(int e) {  // exact 2^e
  return __builtin_bit_cast(float, (unsigned)((127 + e) << 23));
}
__device__ inline void gld_lds16(const void* g, void* l) {
  __builtin_amdgcn_global_load_lds((const __attribute__((address_space(1))) void*)g,
                                   (__attribute__((address_space(3))) void*)l, 16, 0, 0);
}

// ---- weight int4 quant (ints in bf16) + fused cbw = bias-chunk @ W^T -----
__global__ __launch_bounds__(256) void k_wquant_cbw(
    const float* __restrict__ w0, const float* __restrict__ w1,
    const float* __restrict__ w2, const float* __restrict__ bias,
    u16* __restrict__ wq, float* __restrict__ sw, float* __restrict__ cbw,
    int NC) {
  int o = blockIdx.x, t = threadIdx.x;
  const float* w = (o < 2048) ? w0 : ((o < 4096) ? w1 : w2);
  const float* wrow = w + (size_t)(o & 2047) * HDIM;
  const f4_t* row4 = (const f4_t*)wrow;
  f4_t x0 = row4[2 * t], x1 = row4[2 * t + 1];
  float am = 0.f;
#pragma unroll
  for (int j = 0; j < 4; j++) { am = fmaxf(am, fabsf(x0[j])); am = fmaxf(am, fabsf(x1[j])); }
#pragma unroll
  for (int m = 1; m < 64; m <<= 1) am = fmaxf(am, __shfl_xor(am, m));
  __shared__ float red[4];
  if ((t & 63) == 0) red[t >> 6] = am;
  __syncthreads();
  am = fmaxf(fmaxf(red[0], red[1]), fmaxf(red[2], red[3]));
  float s = fmaxf(am / 7.0f, 1e-9f);
  if (t == 0) sw[o] = s;
  bs8 ov;
#pragma unroll
  for (int j = 0; j < 4; j++) {
    float q0 = fminf(fmaxf(rintf(x0[j] / s), -8.f), 7.f);
    float q1 = fminf(fmaxf(rintf(x1[j] / s), -8.f), 7.f);
    ov[j]     = (short)f2bf(q0);      // integer, exact in bf16
    ov[j + 4] = (short)f2bf(q1);
  }
  ((bs8*)(wq + (size_t)o * HDIM))[t] = ov;
  // fused cbw: acc[c] = dot(bias[c,:], w[o,:]) (fp32)
  float acc[NCH];
#pragma unroll
  for (int c = 0; c < NCH; c++) {
    const f4_t* bc = (const f4_t*)(bias + (size_t)c * HDIM);
    f4_t b0 = bc[2 * t], b1 = bc[2 * t + 1];
    float a = 0.f;
#pragma unroll
    for (int j = 0; j < 4; j++) a += x0[j] * b0[j] + x1[j] * b1[j];
    acc[c] = a;
  }
  __shared__ float redc[NCH][4];
#pragma unroll
  for (int c = 0; c < NCH; c++) {
    float a = acc[c];
#pragma unroll
    for (int m = 1; m < 64; m <<= 1) a += __shfl_xor(a, m);
    if ((t & 63) == 0) redc[c][t >> 6] = a;
  }
  __syncthreads();
  if (t < NCH) cbw[t * NC + o] = redc[t][0] + redc[t][1] + redc[t][2] + redc[t][3];
}

// ---- chunk stats, partial pass: 512 blocks (8 ch x 8 slice x 8 rowgrp) ---
__global__ __launch_bounds__(256) void k_stats_p(const float* __restrict__ x,
                                                 float* __restrict__ pmx,
                                                 float* __restrict__ pmn) {
  int rg = blockIdx.x & 7;
  int sl = (blockIdx.x >> 3) & 7;
  int ch = blockIdx.x >> 6;
  int c = (sl << 8) + threadIdx.x;
  const float* base = x + ((size_t)ch * 256 + rg * 32) * HDIM + c;
  float mx = -1e30f, mn = 1e30f;
  for (int r = 0; r < 32; r++) { float v = base[(size_t)r * HDIM]; mx = fmaxf(mx, v); mn = fminf(mn, v); }
  pmx[(size_t)(rg * 8 + ch) * HDIM + c] = mx;
  pmn[(size_t)(rg * 8 + ch) * HDIM + c] = mn;
}

// ---- combine partials -> bias, cmax (one pass, exact) --------------------
__global__ __launch_bounds__(256) void k_stats_c(const float* __restrict__ pmx,
                                                 const float* __restrict__ pmn,
                                                 float* __restrict__ biasO,
                                                 float* __restrict__ cmaxO) {
  int ch = blockIdx.x >> 3;
  int c = ((blockIdx.x & 7) << 8) + threadIdx.x;
  float mx = -1e30f, mn = 1e30f;
#pragma unroll
  for (int rg = 0; rg < 8; rg++) {
    mx = fmaxf(mx, pmx[(size_t)(rg * 8 + ch) * HDIM + c]);
    mn = fminf(mn, pmn[(size_t)(rg * 8 + ch) * HDIM + c]);
  }
  float bi = (mx + mn) * 0.5f;
  biasO[ch * HDIM + c] = bi;
  cmaxO[ch * HDIM + c] = fmaxf(mx - bi, bi - mn);
}

// ---- tmax reduce + per-channel scale s, e2 = 2^idx, tc = (tmax/7)*2^-7 ---
__global__ __launch_bounds__(256) void k_tscale(const float* __restrict__ cmax,
                                                float* __restrict__ scaleO,
                                                float* __restrict__ e2O,
                                                float* __restrict__ tcO) {
  int ch = blockIdx.x, t = threadIdx.x;
  const float* cr = cmax + ch * HDIM;
  float v[8];
  float mx = 0.f;
#pragma unroll
  for (int i = 0; i < 8; i++) { v[i] = cr[i * 256 + t]; mx = fmaxf(mx, v[i]); }
#pragma unroll
  for (int m = 1; m < 64; m <<= 1) mx = fmaxf(mx, __shfl_xor(mx, m));
  __shared__ float red[4];
  __shared__ float tms;
  if ((t & 63) == 0) red[t >> 6] = mx;
  __syncthreads();
  if (t == 0) tms = fmaxf(fmaxf(red[0], red[1]), fmaxf(red[2], red[3]));
  __syncthreads();
  float tmax = tms;
  if (t == 0) tcO[ch] = (tmax / 7.0f) * pow2i(-7);
#pragma unroll
  for (int i = 0; i < 8; i++) {
    int idx = 0;
#pragma unroll
    for (int k = 0; k < 7; k++) idx += (v[i] > tmax * pow2i(k - 7)) ? 1 : 0;
    float s = (tmax * pow2i(idx - 7)) / 7.0f;   // == reference fl(scale)
    scaleO[ch * HDIM + i * 256 + t] = fmaxf(s, 1e-9f);
    e2O[ch * HDIM + i * 256 + t] = pow2i(idx);
  }
}

// ---- activation quant: A' = round((x-bias)/s)*2^idx, bf16-exact ints -----
__global__ __launch_bounds__(256) void k_qdq(const float* __restrict__ x,
                                             const float* __restrict__ bias,
                                             const float* __restrict__ scale,
                                             const float* __restrict__ e2,
                                             u16* __restrict__ out) {
  int row = blockIdx.x, t = threadIdx.x;
  int ch = row >> 8;
  const f4_t* xr = (const f4_t*)(x + (size_t)row * HDIM);
  const f4_t* br = (const f4_t*)(bias + (size_t)ch * HDIM);
  const f4_t* sr = (const f4_t*)(scale + (size_t)ch * HDIM);
  const f4_t* er = (const f4_t*)(e2 + (size_t)ch * HDIM);
  f4_t x0 = xr[2 * t], x1 = xr[2 * t + 1];
  f4_t b0 = br[2 * t], b1 = br[2 * t + 1];
  f4_t s0 = sr[2 * t], s1 = sr[2 * t + 1];
  f4_t e0 = er[2 * t], e1 = er[2 * t + 1];
  bs8 ov;
#pragma unroll
  for (int j = 0; j < 4; j++) {
    float q0 = fminf(fmaxf(rintf((x0[j] - b0[j]) / s0[j]), -8.f), 7.f);
    ov[j] = (short)f2bf(q0 * e0[j]);            // q*2^idx: exact
    float q1 = fminf(fmaxf(rintf((x1[j] - b1[j]) / s1[j]), -8.f), 7.f);
    ov[j + 4] = (short)f2bf(q1 * e1[j]);
  }
  ((bs8*)(out + (size_t)row * HDIM))[t] = ov;
}

// ---- QKV GEMM: 64x128 tile, BK=64, XOR-swizzled LDS, 6 blocks/CU ---------
__global__ __launch_bounds__(256) void k_gemm(
    const u16* __restrict__ A, const u16* __restrict__ B,
    float* __restrict__ o0, float* __restrict__ o1, float* __restrict__ o2,
    const float* __restrict__ cbw, int NC,
    const float* __restrict__ bb0, const float* __restrict__ bb1,
    const float* __restrict__ bb2,
    const float* __restrict__ tc, const float* __restrict__ sw,
    float scl0, float scl1, float scl2) {
  __shared__ u16 smA[64 * 64];
  __shared__ u16 smB[128 * 64];
  int tid = threadIdx.x;
  int wave = tid >> 6, lane = tid & 63;
  int wr = wave >> 1, wc = wave & 1;
  int row0 = blockIdx.y * 64, col0 = blockIdx.x * 128;
  int mat = col0 >> 11;
  float* out = (mat == 0) ? o0 : ((mat == 1) ? o1 : o2);
  const float* bias = (mat == 0) ? bb0 : ((mat == 1) ? bb1 : bb2);
  float scl = (mat == 0) ? scl0 : ((mat == 1) ? scl1 : scl2);
  int chunk = row0 >> 8;
  fx4 zz = {0.f, 0.f, 0.f, 0.f};
  fx4 acc[2][4];
#pragma unroll
  for (int m = 0; m < 2; m++)
#pragma unroll
    for (int n = 0; n < 4; n++) acc[m][n] = zz;

  int srow = wave * 8 + (lane >> 3);
  int scol = (((lane & 7) ^ (lane >> 3)) << 3);
  const u16* Ab = A + (size_t)row0 * HDIM;
  const u16* Bb = B + (size_t)col0 * HDIM;

  int arow = wr * 32 + (lane & 15);
  int brow = wc * 64 + (lane & 15);
  int xA = (arow & 7) << 4;
  int xB = (brow & 7) << 4;
  int kB0 = (lane >> 4) << 4;

  for (int kt = 0; kt < 32; kt++) {
    int kb = kt * 64 + scol;
#pragma unroll
    for (int r = 0; r < 2; r++)
      gld_lds16(Ab + (size_t)(r * 32 + srow) * HDIM + kb,
                (char*)smA + (r * 32 + wave * 8) * 128);
#pragma unroll
    for (int r = 0; r < 4; r++)
      gld_lds16(Bb + (size_t)(r * 32 + srow) * HDIM + kb,
                (char*)smB + (r * 32 + wave * 8) * 128);
    __syncthreads();
#pragma unroll
    for (int kk = 0; kk < 2; kk++) {
      bs8 af[2], bfr[4];
#pragma unroll
      for (int m = 0; m < 2; m++)
        af[m] = *(const bs8*)((const char*)smA + (size_t)((arow + m * 16) * 128 +
                                ((kk * 64 + kB0) ^ xA)));
#pragma unroll
      for (int n = 0; n < 4; n++)
        bfr[n] = *(const bs8*)((const char*)smB + (size_t)((brow + n * 16) * 128 +
                                ((kk * 64 + kB0) ^ xB)));
#pragma unroll
      for (int m = 0; m < 2; m++)
#pragma unroll
        for (int n = 0; n < 4; n++)
          acc[m][n] = __builtin_amdgcn_mfma_f32_16x16x32_bf16(af[m], bfr[n], acc[m][n], 0, 0, 0);
    }
    __syncthreads();
  }
  float tcv = tc[chunk];
  int colb = col0 + wc * 64 + (lane & 15);        // global col
  int rowb = row0 + wr * 32 + ((lane >> 4) << 2);
#pragma unroll
  for (int m = 0; m < 2; m++) {
#pragma unroll
    for (int n = 0; n < 4; n++) {
      int colg = colb + n * 16;
      int colL = colg - (mat << 11);
      float sc = tcv * sw[colg];
      float cb = cbw[chunk * NC + colg] + bias[colL];
#pragma unroll
      for (int j = 0; j < 4; j++) {
        int row = rowb + m * 16 + j;
        out[(size_t)row * HDIM + colL] = (acc[m][n][j] * sc + cb) * scl;
      }
    }
  }
}

// ---- split-K O-GEMM: 64x128 tile, BK=64, K thirds -> raw exact-int -------
__global__ __launch_bounds__(256) void k_gemm_sk(const u16* __restrict__ A,
                                                 const u16* __restrict__ B,
                                                 float* __restrict__ p0,
                                                 float* __restrict__ p1,
                                                 float* __restrict__ p2) {
  __shared__ u16 smA[64 * 64];
  __shared__ u16 smB[128 * 64];
  int tid = threadIdx.x;
  int wave = tid >> 6, lane = tid & 63;
  int wr = wave >> 1, wc = wave & 1;
  int row0 = blockIdx.y * 64, col0 = blockIdx.x * 128;
  int z = blockIdx.z;
  float* out = (z == 0) ? p0 : ((z == 1) ? p1 : p2);
  int kt0 = z * 11;
  int kt1 = (z == 2) ? 32 : (z * 11 + 11);
  fx4 zz = {0.f, 0.f, 0.f, 0.f};
  fx4 acc[2][4];
#pragma unroll
  for (int m = 0; m < 2; m++)
#pragma unroll
    for (int n = 0; n < 4; n++) acc[m][n] = zz;

  int srow = wave * 8 + (lane >> 3);
  int scol = (((lane & 7) ^ (lane >> 3)) << 3);
  const u16* Ab = A + (size_t)row0 * HDIM;
  const u16* Bb = B + (size_t)col0 * HDIM;

  int arow = wr * 32 + (lane & 15);
  int brow = wc * 64 + (lane & 15);
  int xA = (arow & 7) << 4;
  int xB = (brow & 7) << 4;
  int kB0 = (lane >> 4) << 4;

  for (int kt = kt0; kt < kt1; kt++) {
    int kb = kt * 64 + scol;
#pragma unroll
    for (int r = 0; r < 2; r++)
      gld_lds16(Ab + (size_t)(r * 32 + srow) * HDIM + kb,
                (char*)smA + (r * 32 + wave * 8) * 128);
#pragma unroll
    for (int r = 0; r < 4; r++)
      gld_lds16(Bb + (size_t)(r * 32 + srow) * HDIM + kb,
                (char*)smB + (r * 32 + wave * 8) * 128);
    __syncthreads();
#pragma unroll
    for (int kk = 0; kk < 2; kk++) {
      bs8 af[2], bfr[4];
#pragma unroll
      for (int m = 0; m < 2; m++)
        af[m] = *(const bs8*)((const char*)smA + (size_t)((arow + m * 16) * 128 +
                                ((kk * 64 + kB0) ^ xA)));
#pragma unroll
      for (int n = 0; n < 4; n++)
        bfr[n] = *(const bs8*)((const char*)smB + (size_t)((brow + n * 16) * 128 +
                                ((kk * 64 + kB0) ^ xB)));
#pragma unroll
      for (int m = 0; m < 2; m++)
#pragma unroll
        for (int n = 0; n < 4; n++)
          acc[m][n] = __builtin_amdgcn_mfma_f32_16x16x32_bf16(af[m], bfr[n], acc[m][n], 0, 0, 0);
    }
    __syncthreads();
  }
  int colb = col0 + wc * 64 + (lane & 15);
  int rowb = row0 + wr * 32 + ((lane >> 4) << 2);
#pragma unroll
  for (int m = 0; m < 2; m++)
#pragma unroll
    for (int n = 0; n < 4; n++)
#pragma unroll
      for (int j = 0; j < 4; j++)
        out[(size_t)(rowb + m * 16 + j) * HDIM + colb + n * 16] = acc[m][n][j];
}

// ---- split-K combine + epilogue: out = ((p0+p1+p2)*sc + cb) -------------
__global__ __launch_bounds__(256) void k_fin(const float* __restrict__ p0,
                                             const float* __restrict__ p1,
                                             const float* __restrict__ p2,
                                             const float* __restrict__ cbw,
                                             const float* __restrict__ bias,
                                             const float* __restrict__ tc,
                                             const float* __restrict__ sw,
                                             float* __restrict__ out) {
  int row = blockIdx.x, t = threadIdx.x;
  int chunk = row >> 8;
  float tcv = tc[chunk];
  const f4_t* a = (const f4_t*)(p0 + (size_t)row * HDIM);
  const f4_t* b = (const f4_t*)(p1 + (size_t)row * HDIM);
  const f4_t* c_ = (const f4_t*)(p2 + (size_t)row * HDIM);
  f4_t* o = (f4_t*)(out + (size_t)row * HDIM);
#pragma unroll
  for (int u = 0; u < 2; u++) {
    f4_t x = a[2 * t + u], y = b[2 * t + u], w = c_[2 * t + u];
    f4_t r;
#pragma unroll
    for (int j = 0; j < 4; j++) {
      int c = (2 * t + u) * 4 + j;
      float sc = tcv * sw[c];
      float cb = cbw[chunk * HDIM + c] + bias[c];
      r[j] = ((x[j] + y[j] + w[j]) * sc + cb) * 1.0f;
    }
    o[2 * t + u] = r;
  }
}

// ---- K/V hi-lo split + V transpose, pre-swizzled tile layout (ONCE) ------
__global__ __launch_bounds__(256) void k_split(const float* __restrict__ Kf,
                                               const float* __restrict__ Vf,
                                               u16* __restrict__ Khg,
                                               u16* __restrict__ Klg,
                                               u16* __restrict__ Vhg,
                                               u16* __restrict__ Vlg) {
  __shared__ u16 Th[4096], Tl[4096];
  int t = threadIdx.x;
  int ti = blockIdx.x & 15, h = (blockIdx.x >> 4) & 31, b = blockIdx.x >> 9;
  size_t rowStart = (size_t)b * 1024 + ti * 64;
  int colh = h * 64;
  size_t tbase = ((size_t)((b * 32 + h) * 16 + ti)) * 4096;
  int kr = t >> 2, d0 = (t & 3) << 4;
  int xk = (kr & 7) << 3;
  const float* kp = Kf + (rowStart + kr) * HDIM + colh + d0;
  const float* vp = Vf + (rowStart + kr) * HDIM + colh + d0;
  f4_t kv[4], vv[4];
#pragma unroll
  for (int qd = 0; qd < 4; qd++) { kv[qd] = *(const f4_t*)(kp + 4 * qd); vv[qd] = *(const f4_t*)(vp + 4 * qd); }
  bs8 h0, l0, h1, l1;
#pragma unroll
  for (int j = 0; j < 4; j++) {
    float x = kv[0][j]; u16 hh = f2bf(x); h0[j] = (short)hh; l0[j] = (short)f2bf(x - bf2f(hh));
    x = kv[1][j]; hh = f2bf(x); h0[j + 4] = (short)hh; l0[j + 4] = (short)f2bf(x - bf2f(hh));
    x = kv[2][j]; hh = f2bf(x); h1[j] = (short)hh; l1[j] = (short)f2bf(x - bf2f(hh));
    x = kv[3][j]; hh = f2bf(x); h1[j + 4] = (short)hh; l1[j + 4] = (short)f2bf(x - bf2f(hh));
  }
  *(bs8*)(Khg + tbase + kr * 64 + (d0 ^ xk)) = h0;
  *(bs8*)(Klg + tbase + kr * 64 + (d0 ^ xk)) = l0;
  *(bs8*)(Khg + tbase + kr * 64 + ((d0 + 8) ^ xk)) = h1;
  *(bs8*)(Klg + tbase + kr * 64 + ((d0 + 8) ^ xk)) = l1;
#pragma unroll
  for (int qd = 0; qd < 4; qd++)
#pragma unroll
    for (int j = 0; j < 4; j++) {
      int d = d0 + 4 * qd + j;
      float x = vv[qd][j]; u16 hh = f2bf(x);
      int vi = d * 64 + (kr ^ ((d & 7) << 3));
      Th[vi] = hh; Tl[vi] = f2bf(x - bf2f(hh));
    }
  __syncthreads();
  *(bs8*)(Vhg + tbase + t * 16) = *(const bs8*)&Th[t * 16];
  *(bs8*)(Vhg + tbase + t * 16 + 8) = *(const bs8*)&Th[t * 16 + 8];
  *(bs8*)(Vlg + tbase + t * 16) = *(const bs8*)&Tl[t * 16];
  *(bs8*)(Vlg + tbase + t * 16 + 8) = *(const bs8*)&Tl[t * 16 + 8];
}

// ---- flash attention, SWAPPED QK^T (round-15 proven version, FROZEN) -----
__global__ __launch_bounds__(256) void k_attn(const float* __restrict__ Q,
                                              const u16* __restrict__ Khg,
                                              const u16* __restrict__ Klg,
                                              const u16* __restrict__ Vhg,
                                              const u16* __restrict__ Vlg,
                                              float* __restrict__ O) {
  __shared__ u16 Kh[64 * 64], Kl[64 * 64];   // [key][d^((key&7)<<3)]
  __shared__ u16 Vh[64 * 64], Vl[64 * 64];   // [d][key^((d&7)<<3)]
  int tid = threadIdx.x, wave = tid >> 6, lane = tid & 63;
  int l15 = lane & 15, l4 = lane >> 4;
  int lid = blockIdx.x;
  int xcd = lid & 7, jj = lid >> 3;
  int pair = xcd * 8 + (jj >> 4);     // 64 (b,h) pairs; 8 per XCD
  int qt = jj & 15;                   // 16 q-tiles of 64 rows
  int h = pair & 31, b = pair >> 5;
  size_t rowStart = (size_t)b * 1024;
  int colh = h * 64;
  int qbase = qt * 64 + wave * 16;
  size_t hbase = (size_t)pair * 16 * 4096;   // element base of this (b,h)

  bs8 qh[2], ql[2];
#pragma unroll
  for (int kk = 0; kk < 2; kk++) {
    const float* qp = Q + (rowStart + qbase + l15) * HDIM + colh + kk * 32 + (l4 << 3);
    f4_t a0 = *(const f4_t*)qp;
    f4_t a1 = *(const f4_t*)(qp + 4);
#pragma unroll
    for (int j = 0; j < 4; j++) {
      float x = a0[j]; u16 hh = f2bf(x);
      qh[kk][j] = (short)hh; ql[kk][j] = (short)f2bf(x - bf2f(hh));
      x = a1[j]; hh = f2bf(x);
      qh[kk][j + 4] = (short)hh; ql[kk][j + 4] = (short)f2bf(x - bf2f(hh));
    }
  }

  fx4 zz = {0.f, 0.f, 0.f, 0.f};
  fx4 oacc[4];
  float mrun = -1e30f, lrun = 0.f;
#pragma unroll
  for (int n = 0; n < 4; n++) oacc[n] = zz;

  const u16* garr = (wave == 0) ? Khg : (wave == 1) ? Klg : (wave == 2) ? Vhg : Vlg;
  u16* larr = (wave == 0) ? Kh : (wave == 1) ? Kl : (wave == 2) ? Vh : Vl;

  int srcA = l15 + ((lane & 16) << 1);   // l15 + 32*(l4&1)
  int srcB = srcA + 16;
  int hiSel = l4 >> 1;

  for (int ti = 0; ti < 16; ti++) {
    const u16* gsrc = garr + hbase + (size_t)ti * 4096 + lane * 8;
#pragma unroll
    for (int seg = 0; seg < 8; seg++)
      gld_lds16(gsrc + seg * 512, larr + seg * 512);
    __syncthreads();

    fx4 sf[4];
#pragma unroll
    for (int n = 0; n < 4; n++) sf[n] = zz;
    __builtin_amdgcn_s_setprio(1);
#pragma unroll
    for (int kk = 0; kk < 2; kk++) {
      int colr = kk * 32 + (l4 << 3);
#pragma unroll
      for (int n = 0; n < 4; n++) {
        int row = n * 16 + l15;
        int ko = row * 64 + (colr ^ ((row & 7) << 3));
        bs8 bh = *(const bs8*)&Kh[ko];
        bs8 bl = *(const bs8*)&Kl[ko];
        sf[n] = __builtin_amdgcn_mfma_f32_16x16x32_bf16(bl, ql[kk], sf[n], 0, 0, 0);
        sf[n] = __builtin_amdgcn_mfma_f32_16x16x32_bf16(bh, ql[kk], sf[n], 0, 0, 0);
        sf[n] = __builtin_amdgcn_mfma_f32_16x16x32_bf16(bl, qh[kk], sf[n], 0, 0, 0);
        sf[n] = __builtin_amdgcn_mfma_f32_16x16x32_bf16(bh, qh[kk], sf[n], 0, 0, 0);
      }
    }
    __builtin_amdgcn_s_setprio(0);
    float tm = sf[0][0];
#pragma unroll
    for (int n = 0; n < 4; n++)
#pragma unroll
      for (int j = 0; j < 4; j++) tm = fmaxf(tm, sf[n][j]);
    tm = fmaxf(tm, __shfl_xor(tm, 16));
    tm = fmaxf(tm, __shfl_xor(tm, 32));
    float mn = fmaxf(mrun, tm);
    float corr = __expf(mrun - mn);
    mrun = mn;
    float rs = 0.f;
#pragma unroll
    for (int n = 0; n < 4; n++)
#pragma unroll
      for (int j = 0; j < 4; j++) { float p = __expf(sf[n][j] - mn); sf[n][j] = p; rs += p; }
    rs += __shfl_xor(rs, 16);
    rs += __shfl_xor(rs, 32);
    lrun = lrun * corr + rs;
#pragma unroll
    for (int n = 0; n < 4; n++)
#pragma unroll
      for (int j = 0; j < 4; j++) oacc[n][j] *= corr;

    u32 hiw[4][2], low[4][2];
#pragma unroll
    for (int n = 0; n < 4; n++) {
      u16 hh0 = f2bf(sf[n][0]), hh1 = f2bf(sf[n][1]);
      u16 hh2 = f2bf(sf[n][2]), hh3 = f2bf(sf[n][3]);
      u16 ll0 = f2bf(sf[n][0] - bf2f(hh0)), ll1 = f2bf(sf[n][1] - bf2f(hh1));
      u16 ll2 = f2bf(sf[n][2] - bf2f(hh2)), ll3 = f2bf(sf[n][3] - bf2f(hh3));
      hiw[n][0] = (u32)hh0 | ((u32)hh1 << 16);
      hiw[n][1] = (u32)hh2 | ((u32)hh3 << 16);
      low[n][0] = (u32)ll0 | ((u32)ll1 << 16);
      low[n][1] = (u32)ll2 | ((u32)ll3 << 16);
    }
    bs8 ph[2], pl[2];
#pragma unroll
    for (int kkv = 0; kkv < 2; kkv++) {
      u4_t wh, wl;
#pragma unroll
      for (int half = 0; half < 2; half++) {
        int src = half ? srcB : srcA;
#pragma unroll
        for (int pr = 0; pr < 2; pr++) {
          int a0 = __shfl((int)hiw[2 * kkv][pr], src);
          int a1 = __shfl((int)hiw[2 * kkv + 1][pr], src);
          wh[half * 2 + pr] = (u32)(hiSel ? a1 : a0);
          int b0 = __shfl((int)low[2 * kkv][pr], src);
          int b1 = __shfl((int)low[2 * kkv + 1][pr], src);
          wl[half * 2 + pr] = (u32)(hiSel ? b1 : b0);
        }
      }
      ph[kkv] = __builtin_bit_cast(bs8, wh);
      pl[kkv] = __builtin_bit_cast(bs8, wl);
    }

    __builtin_amdgcn_s_setprio(1);
#pragma unroll
    for (int kkv = 0; kkv < 2; kkv++) {
      int colr = kkv * 32 + (l4 << 3);
#pragma unroll
      for (int n = 0; n < 4; n++) {
        int vrow = n * 16 + l15;
        int vo = vrow * 64 + (colr ^ ((vrow & 7) << 3));
        bs8 vh = *(const bs8*)&Vh[vo];
        bs8 vl = *(const bs8*)&Vl[vo];
        oacc[n] = __builtin_amdgcn_mfma_f32_16x16x32_bf16(vl, pl[kkv], oacc[n], 0, 0, 0);
        oacc[n] = __builtin_amdgcn_mfma_f32_16x16x32_bf16(vh, pl[kkv], oacc[n], 0, 0, 0);
        oacc[n] = __builtin_amdgcn_mfma_f32_16x16x32_bf16(vl, ph[kkv], oacc[n], 0, 0, 0);
        oacc[n] = __builtin_amdgcn_mfma_f32_16x16x32_bf16(vh, ph[kkv], oacc[n], 0, 0, 0);
      }
    }
    __builtin_amdgcn_s_setprio(0);
    __syncthreads();
  }
  size_t token = rowStart + qbase + l15;
#pragma unroll
  for (int n = 0; n < 4; n++) {
    f4_t r;
#pragma unroll
    for (int j = 0; j < 4; j++) r[j] = oacc[n][j] / lrun;
    *(f4_t*)(O + token * HDIM + colh + n * 16 + (l4 << 2)) = r;
  }
}

extern "C" void kernel_launch(void* const* d_in, const int* in_sizes, int n_in,
                              void* d_out, int out_size, void* d_ws, size_t ws_size,
                              hipStream_t stream) {
  const float* hs = (const float*)d_in[0];
  const float* qw = (const float*)d_in[1];
  const float* kw = (const float*)d_in[2];
  const float* vw = (const float*)d_in[3];
  const float* ow = (const float*)d_in[4];
  const float* qb = (const float*)d_in[5];
  const float* kb = (const float*)d_in[6];
  const float* vb = (const float*)d_in[7];
  const float* ob = (const float*)d_in[8];

  char* ws = (char*)d_ws;
  const size_t MB = 1u << 20;
  // Timeline-shared workspace (ws >= 82 MB, proven rounds 3-15):
  //  [0,32MB):  A: wqQKV(24)+actA(8) -> B: K/V split arrays -> C: p0/p1
  //  [32,48MB): Qf (stage-2 stats partials after attn)
  //  [48,64MB): stage-1 stats partials -> Kf -> actA2
  //  [64,80MB): Vf -> wqO
  //  [80MB+):   small stats buffers     p2 = d_out (ctx dead after qdq)
  u16* wqQKV = (u16*)(ws + 0 * MB);
  u16* actA  = (u16*)(ws + 24 * MB);
  u16* Khg   = (u16*)(ws + 0 * MB);
  u16* Klg   = (u16*)(ws + 8 * MB);
  u16* Vhg   = (u16*)(ws + 16 * MB);
  u16* Vlg   = (u16*)(ws + 24 * MB);
  float* p0  = (float*)(ws + 0 * MB);
  float* p1  = (float*)(ws + 16 * MB);
  float* Qf  = (float*)(ws + 32 * MB);
  float* Kf  = (float*)(ws + 48 * MB);
  float* Vf  = (float*)(ws + 64 * MB);
  u16* actA2 = (u16*)(ws + 48 * MB);   // over Kf (free after k_split)
  u16* wqO   = (u16*)(ws + 64 * MB);   // over Vf (free after k_split)
  float* pmx1 = (float*)(ws + 48 * MB);          // stage-1 partials (pre-Kf)
  float* pmn1 = pmx1 + 64 * HDIM;
  float* pmx2 = (float*)(ws + 32 * MB);          // stage-2 partials (Qf dead)
  float* pmn2 = pmx2 + 64 * HDIM;
  float* sm  = (float*)(ws + 80 * MB);
  float* bias1  = sm;
  float* cmax1  = bias1 + NCH * HDIM;
  float* scale1 = cmax1 + NCH * HDIM;
  float* e2_1   = scale1 + NCH * HDIM;
  float* bias2  = e2_1 + NCH * HDIM;
  float* cmax2  = bias2 + NCH * HDIM;
  float* scale2 = cmax2 + NCH * HDIM;
  float* e2_2   = scale2 + NCH * HDIM;
  float* cbwQKV = e2_2 + NCH * HDIM;     // [NCH][6144]
  float* swQKV  = cbwQKV + NCH * 3 * HDIM;
  float* cbwO   = swQKV + 3 * HDIM;      // [NCH][2048]
  float* swO    = cbwO + NCH * HDIM;
  float* tc1    = swO + HDIM;
  float* tc2    = tc1 + NCH;
  float* ctx = (float*)d_out;
  float* p2  = (float*)d_out;            // ctx dead after stage-2 qdq

  k_stats_p<<<512, 256, 0, stream>>>(hs, pmx1, pmn1);
  k_stats_c<<<64, 256, 0, stream>>>(pmx1, pmn1, bias1, cmax1);
  k_tscale<<<8, 256, 0, stream>>>(cmax1, scale1, e2_1, tc1);
  k_qdq<<<2048, 256, 0, stream>>>(hs, bias1, scale1, e2_1, actA);
  k_wquant_cbw<<<6144, 256, 0, stream>>>(qw, kw, vw, bias1, wqQKV, swQKV, cbwQKV, 3 * HDIM);
  k_gemm<<<dim3(48, 32), 256, 0, stream>>>(actA, wqQKV, Qf, Kf, Vf,
                                           cbwQKV, 3 * HDIM, qb, kb, vb,
                                           tc1, swQKV, 0.125f, 1.0f, 1.0f);
  k_split<<<1024, 256, 0, stream>>>(Kf, Vf, Khg, Klg, Vhg, Vlg);
  k_attn<<<1024, 256, 0, stream>>>(Qf, Khg, Klg, Vhg, Vlg, ctx);
  k_stats_p<<<512, 256, 0, stream>>>(ctx, pmx2, pmn2);
  k_stats_c<<<64, 256, 0, stream>>>(pmx2, pmn2, bias2, cmax2);
  k_tscale<<<8, 256, 0, stream>>>(cmax2, scale2, e2_2, tc2);
  k_qdq<<<2048, 256, 0, stream>>>(ctx, bias2, scale2, e2_2, actA2);
  k_wquant_cbw<<<2048, 256, 0, stream>>>(ow, ow, ow, bias2, wqO, swO, cbwO, HDIM);
  k_gemm_sk<<<dim3(16, 32, 3), 256, 0, stream>>>(actA2, wqO, p0, p1, p2);
  k_fin<<<2048, 256, 0, stream>>>(p0, p1, p2, cbwO, ob, tc2, swO, (float*)d_out);
}